// Round 16
// baseline (129.830 us; speedup 1.0000x reference)
//
#include <hip/hip_runtime.h>
#include <math.h>

#define NH 64
#define NW 64
#define NB 4
#define CHI 256
#define CHO 256
// xT layout is CHUNK-OUTER: [B][8 cc][66*66 pos][32 ch]  (bf16, zero halo rows/cols)
#define XT_B (8 * 4356 * 32)   // per-batch elements; 4356 = 66*66

// LDS window record stride: 40 shorts (80B), 16B-aligned for b128.
#define WREC 40
#define WINSZ (594 * WREC)     // shorts per 9-row window

typedef __attribute__((ext_vector_type(8))) short bf16x8;   // MFMA A/B frag (4 VGPR)
typedef __attribute__((ext_vector_type(4))) float f32x4;    // MFMA C/D frag

static __device__ __forceinline__ unsigned short f2bf(float f) {
    unsigned int u = __float_as_uint(f);
    u += 0x7fffu + ((u >> 16) & 1u);     // RNE
    return (unsigned short)(u >> 16);
}
static __device__ __forceinline__ float bflo(unsigned int p) { return __uint_as_float(p << 16); }
// hi bf16 WITHOUT masking (low 16 bits = other channel's bf16, <=2^-8 relative junk)
static __device__ __forceinline__ float bfhij(unsigned int p) { return __uint_as_float(p); }
static __device__ __forceinline__ unsigned int pkbf(float a, float b) {
    unsigned int r;
    asm("v_cvt_pk_bf16_f32 %0, %1, %2" : "=v"(r) : "v"(a), "v"(b));
    return r;
}

// lgkm-only barrier: ds ops drained, in-flight global loads ride across.
#define BAR_LGKM() asm volatile("s_waitcnt lgkmcnt(0)\n\ts_barrier" ::: "memory")

// ws layout:
//   wB   bf16 [72][256 o][32 kin]   ks = cc*9+kt
//   wOB  bf16 [72][32 oc][32 kin]
//   xT   bf16 [B][8][4356][32]  chunk-outer

// grid 1673: [0,576) wB pack (dense f4) | [576,640) wOB pack (dense f4) |
//            [640] wOB zero tail | [641,1153) transpose | [1153,1673) halo zero
__global__ __launch_bounds__(256) void prep_all(const float* __restrict__ weight,
                                                const float* __restrict__ w_off,
                                                const float* __restrict__ x,
                                                unsigned short* __restrict__ wB,
                                                unsigned short* __restrict__ wOB,
                                                unsigned short* __restrict__ xT) {
    __shared__ unsigned short sT[64 * 134];
    int bid = blockIdx.x, tid = threadIdx.x;
    if (bid < 576) {
        int idx4 = bid * 256 + tid;
        float4 v = ((const float4*)weight)[idx4];
        float vv[4] = {v.x, v.y, v.z, v.w};
        int i0 = idx4 * 4;
#pragma unroll
        for (int j = 0; j < 4; ++j) {
            int i = i0 + j;
            int o = i / 2304, r = i - o * 2304;
            int c = r / 9, kt = r - c * 9;
            wB[(((c >> 5) * 9 + kt) * 256 + o) * 32 + (c & 31)] = f2bf(vv[j]);
        }
    } else if (bid < 640) {
        int idx4 = (bid - 576) * 256 + tid;
        if (idx4 < 15552) {
            float4 v = ((const float4*)w_off)[idx4];
            float vv[4] = {v.x, v.y, v.z, v.w};
            int i0 = idx4 * 4;
#pragma unroll
            for (int j = 0; j < 4; ++j) {
                int i = i0 + j;
                int oc = i / 2304, r = i - oc * 2304;
                int c = r / 9, kt = r - c * 9;
                wOB[(((c >> 5) * 9 + kt) * 32 + oc) * 32 + (c & 31)] = f2bf(vv[j]);
            }
        }
    } else if (bid == 640) {
        for (int k = tid; k < 11520; k += 256) {
            int ks = k / 160, r = k - ks * 160;
            int oc = 27 + r / 32, kin = r & 31;
            wOB[(ks * 32 + oc) * 32 + kin] = 0;
        }
    } else if (bid < 1153) {
        int bid2 = bid - 641;                  // 0..511
        int b = bid2 >> 7, rem = bid2 & 127;
        int y = rem >> 1, chalf = rem & 1;
        int c0 = chalf * 128;
        for (int rep = 0; rep < 8; ++rep) {
            int idx = rep * 256 + tid;         // 0..2047
            int c = idx >> 4, p4 = (idx & 15) * 4;
            const float* src = x + (((size_t)b * CHI + c0 + c) * 64 + y) * 64 + p4;
            float4 v = *(const float4*)src;
            sT[(p4 + 0) * 134 + c] = f2bf(v.x);
            sT[(p4 + 1) * 134 + c] = f2bf(v.y);
            sT[(p4 + 2) * 134 + c] = f2bf(v.z);
            sT[(p4 + 3) * 134 + c] = f2bf(v.w);
        }
        __syncthreads();
        unsigned int* xtu = (unsigned int*)xT;
        for (int rep = 0; rep < 4; ++rep) {
            int idx = rep * 256 + tid;         // 0..1023
            int px = idx >> 4, cc_l = (idx >> 2) & 3, q4 = idx & 3;
            int cc = chalf * 4 + cc_l;
            int cb = cc_l * 32 + q4 * 8;
            const unsigned int* sp = (const unsigned int*)&sT[px * 134 + cb];
            uint4 vv;
            vv.x = sp[0]; vv.y = sp[1]; vv.z = sp[2]; vv.w = sp[3];
            *(uint4*)&xtu[((size_t)(b * 8 + cc) * 4356
                           + (size_t)(y + 1) * 66 + (px + 1)) * 16 + q4 * 4] = vv;
        }
    } else {
        int flat = (bid - 1153) * 256 + tid;   // 0..133119 uints
        int b = flat / 33280, r = flat - b * 33280;
        int chunk = r / 4160, rr = r - chunk * 4160;
        int p_ = rr >> 4, ku = rr & 15;
        int pos;
        if (p_ < 66)       pos = p_;
        else if (p_ < 132) pos = 65 * 66 + (p_ - 66);
        else { int qq = p_ - 132; int side = qq & 1; int row = 1 + (qq >> 1);
               pos = row * 66 + (side ? 65 : 0); }
        unsigned int* xtu = (unsigned int*)xT;
        xtu[((size_t)(b * 8 + chunk) * 4356 + pos) * 16 + ku] = 0;
    }
}

// ---- fused: offset GEMM prologue + deformable sampling + MFMA GEMM + BN + ReLU ----
// r16: 1024 threads (16 waves, 4/SIMD) at the SAME LDS/interval structure as r15.
// r15's barrier-halving only gave 2us -> the stall is per-interval dependency-chain
// latency with 2 waves/SIMD. Doubling TLP + halving per-thread producer work is the
// remaining lever. __launch_bounds__(1024,2): empirical cap = 256/2 = 128 VGPR
// (live set ~110; 4 waves x 128 = 512 = SIMD pool, launchable). Consumer roles
// nb(8: 32-oc) x kh(2); producer slice-pair split by ip = (tid>>8)&1. Slot/barrier
// topology identical to r15 (verified); each sA slot written by one disjoint
// 256-thread group per interval; producer khp = tid>>9 == consumer kh = q>>3.
__global__ __launch_bounds__(1024, 2) void dcn_fused(
        const unsigned short* __restrict__ xT,
        const unsigned short* __restrict__ wOB,
        const unsigned short* __restrict__ wB,
        const float* __restrict__ b_off,
        const float* __restrict__ bias, const float* __restrict__ gamma,
        const float* __restrict__ beta, const float* __restrict__ rmean,
        const float* __restrict__ rvar, float* __restrict__ out) {
    // LDS: s_po [0,9216) s_cw [9216,18432) fixed.
    //   sA   [18432,59392): 8 slots (2 sets x 2 slices x 2 streams) x 64px x 40B
    //   sWin [59392,154432): 2 windows x 594 rec x 80B = 47520B each
    //   sOff (33792B) and sOut (66560B) alias sWin (prologue / epilogue only)
    __shared__ __align__(16) unsigned char smem[154432];
    int4*   s_po = (int4*)smem;                                 // [576], pre-scaled x WREC
    float4* s_cw = (float4*)(smem + 9216);                      // [576]
    unsigned short* sA = (unsigned short*)(smem + 18432);
    unsigned short* sWin = (unsigned short*)(smem + 59392);
    float* sOff = (float*)(smem + 59392);
    float (*sOut)[260] = (float(*)[260])(smem + 59392);         // [64][260]

    int id = blockIdx.x;                        // 256 blocks
    int xcd = id & 7, sl = id >> 3;             // 32 blocks per XCD
    int b = xcd >> 1;                           // batch pinned to XCD pair (xT L2 reuse)
    int h = (xcd & 1) * 32 + sl;                // output row

    int tid = threadIdx.x;
    int lane = tid & 63, q = tid >> 6;          // q = wave 0..15
    int ln = lane & 15, lk = lane >> 4;
    int nb = q & 7, kh = q >> 3;                // consumer: 32-oc group, K-half

    const unsigned short* xTfull = xT + (size_t)b * XT_B;
    const bf16x8* wOBv = (const bf16x8*)wOB;
    const bf16x8* wBv  = (const bf16x8*)wB;

    // ---- offset-conv prologue: om = xT . wOB (M=64, N=32, K=2304), 16 waves ----
    // roles: omt = px half, ont = oc 16-half, okq = K-quarter (2 cc each)  [r4-verified]
    {
        int omt = q & 1, ont = (q >> 1) & 1, okq = q >> 2;
        int px0 = omt * 32 + ln;
        int posb = (h + 1) * 66 + 1 + px0;
        f32x4 oa0 = {0.f,0.f,0.f,0.f}, oa1 = {0.f,0.f,0.f,0.f};
        for (int cc = okq * 2; cc < okq * 2 + 2; ++cc) {
#pragma unroll
            for (int kt = 0; kt < 9; ++kt) {
                int pos = posb + (kt / 3 - 1) * 66 + (kt % 3 - 1);
                bf16x8 A0 = *(const bf16x8*)&xTfull[((size_t)cc * 4356 + pos) * 32 + lk * 8];
                bf16x8 A1 = *(const bf16x8*)&xTfull[((size_t)cc * 4356 + pos + 16) * 32 + lk * 8];
                bf16x8 B0 = wOBv[((size_t)(cc * 9 + kt) * 32 + ont * 16 + ln) * 4 + lk];
                oa0 = __builtin_amdgcn_mfma_f32_16x16x32_bf16(A0, B0, oa0, 0, 0, 0);
                oa1 = __builtin_amdgcn_mfma_f32_16x16x32_bf16(A1, B0, oa1, 0, 0, 0);
            }
        }
#pragma unroll
        for (int r = 0; r < 4; ++r) {
            int row0 = omt * 32 + lk * 4 + r;
            sOff[(okq * 64 + row0) * 33 + ont * 16 + ln]      = oa0[r];
            sOff[(okq * 64 + row0 + 16) * 33 + ont * 16 + ln] = oa1[r];
        }
    }
    BAR_LGKM();

    // ---- bilinear metadata; corner offsets pre-scaled by WREC (shorts) ----
    for (int p = tid; p < 576; p += 1024) {
        int k = p >> 6, pwl = p & 63;
        float dy = b_off[k], dx = b_off[k + 9], mp = b_off[k + 18];
#pragma unroll
        for (int jq = 0; jq < 4; ++jq) {
            dy += sOff[(jq * 64 + pwl) * 33 + k];
            dx += sOff[(jq * 64 + pwl) * 33 + k + 9];
            mp += sOff[(jq * 64 + pwl) * 33 + k + 18];
        }
        float mv = 1.f / (1.f + __expf(-mp));
        float py  = (float)h   + (float)(k / 3 - 1) + dy;
        float pxf = (float)pwl + (float)(k % 3 - 1) + dx;
        float y0f = floorf(py), x0f = floorf(pxf);
        int y0 = (int)y0f, x0 = (int)x0f;
        float ly = py - y0f, lx = pxf - x0f;
        int y0c = min(max(y0, -1), 64), y1c = min(max(y0 + 1, -1), 64);
        int x0c = min(max(x0, -1), 64), x1c = min(max(x0 + 1, -1), 64);
        int wy0 = min(max(y0c + 4 - h, 0), 8), wy1 = min(max(y1c + 4 - h, 0), 8);
        int rx0 = x0c + 1, rx1 = x1c + 1;
        s_po[p] = make_int4((wy0 * 66 + rx0) * WREC, (wy0 * 66 + rx1) * WREC,
                            (wy1 * 66 + rx0) * WREC, (wy1 * 66 + rx1) * WREC);
        s_cw[p] = make_float4((1.f - ly) * (1.f - lx) * mv, (1.f - ly) * lx * mv,
                              ly * (1.f - lx) * mv,         ly * lx * mv);
    }

    // producer role: cg8 (16B chunk of an 80B record), pxl 0..63,
    // sl4 = tid>>8: khp = sl4>>1 (stream, == kh), ip = sl4&1 (slice of the pair)
    int cg8 = tid & 3, pxl = (tid >> 2) & 63;
    int sl4 = tid >> 8, khp = sl4 >> 1, ip = sl4 & 1;

    f32x4 zf = {0.f, 0.f, 0.f, 0.f};
    f32x4 acc[4][2] = {{zf,zf},{zf,zf},{zf,zf},{zf,zf}};

// stage 9-row window (dense 16B granules); 512 threads per stream
#define STAGE(pp) do { int ccg_ = khp * 4 + (pp);                              \
        unsigned short* wd_ = sWin + khp * WINSZ;                              \
        int t_ = tid & 511;                                                    \
        for (int rr_ = 0; rr_ < 5; ++rr_) {                                    \
            int idx_ = rr_ * 512 + t_;                                         \
            if (idx_ < 2376) {                                                 \
                int wr_ = idx_ / 264, rg_ = idx_ - wr_ * 264;                  \
                int pr_ = rg_ >> 2, g_ = rg_ & 3;                              \
                int gy_ = min(max(h - 3 + wr_, 0), 65);                        \
                const unsigned short* sp_ = xTfull                             \
                    + ((size_t)(ccg_ * 4356 + gy_ * 66) << 5) + rg_ * 8;       \
                *(uint4*)(wd_ + (size_t)(wr_ * 66 + pr_) * WREC + g_ * 8)      \
                    = *(const uint4*)sp_;                                      \
            }                                                                  \
        }                                                                      \
    } while (0)

// gather 4 corners of tap kt (offsets pre-scaled), weight, pack, write sA slot
#define PACK(kt_, buf_) do {                                                   \
        int4 o4_ = s_po[(kt_) * 64 + pxl];                                     \
        const unsigned short* wb_ = sWin + khp * WINSZ + cg8 * 8;              \
        uint4 C00 = *(const uint4*)(wb_ + (size_t)o4_.x);                      \
        uint4 C01 = *(const uint4*)(wb_ + (size_t)o4_.y);                      \
        uint4 C10 = *(const uint4*)(wb_ + (size_t)o4_.z);                      \
        uint4 C11 = *(const uint4*)(wb_ + (size_t)o4_.w);                      \
        float4 w_ = s_cw[(kt_) * 64 + pxl];                                    \
        uint4 pk_;                                                             \
        pk_.x = pkbf(w_.x*bflo(C00.x)+w_.y*bflo(C01.x)+w_.z*bflo(C10.x)+w_.w*bflo(C11.x), \
                     w_.x*bfhij(C00.x)+w_.y*bfhij(C01.x)+w_.z*bfhij(C10.x)+w_.w*bfhij(C11.x)); \
        pk_.y = pkbf(w_.x*bflo(C00.y)+w_.y*bflo(C01.y)+w_.z*bflo(C10.y)+w_.w*bflo(C11.y), \
                     w_.x*bfhij(C00.y)+w_.y*bfhij(C01.y)+w_.z*bfhij(C10.y)+w_.w*bfhij(C11.y)); \
        pk_.z = pkbf(w_.x*bflo(C00.z)+w_.y*bflo(C01.z)+w_.z*bflo(C10.z)+w_.w*bflo(C11.z), \
                     w_.x*bfhij(C00.z)+w_.y*bfhij(C01.z)+w_.z*bfhij(C10.z)+w_.w*bfhij(C11.z)); \
        pk_.w = pkbf(w_.x*bflo(C00.w)+w_.y*bflo(C01.w)+w_.z*bflo(C10.w)+w_.w*bflo(C11.w), \
                     w_.x*bfhij(C00.w)+w_.y*bfhij(C01.w)+w_.z*bfhij(C10.w)+w_.w*bfhij(C11.w)); \
        *(uint4*)&sA[(buf_) * 2560 + pxl * 40 + cg8 * 8] = pk_;                \
    } while (0)

// consume one slice from sA slot into acc with weight set bf_ (nb = 32-oc group)
#define CONSUME(slot_, bf_) do {                                               \
        const unsigned short* pA_ = &sA[(slot_) * 2560];                       \
        bf16x8 a0_ = *(const bf16x8*)&pA_[(0 * 16 + ln) * 40 + lk * 8];        \
        bf16x8 a1_ = *(const bf16x8*)&pA_[(1 * 16 + ln) * 40 + lk * 8];        \
        bf16x8 a2_ = *(const bf16x8*)&pA_[(2 * 16 + ln) * 40 + lk * 8];        \
        bf16x8 a3_ = *(const bf16x8*)&pA_[(3 * 16 + ln) * 40 + lk * 8];        \
        _Pragma("unroll")                                                      \
        for (int j_ = 0; j_ < 2; ++j_) {                                       \
            acc[0][j_] = __builtin_amdgcn_mfma_f32_16x16x32_bf16(a0_, bf_[j_], acc[0][j_], 0, 0, 0); \
            acc[1][j_] = __builtin_amdgcn_mfma_f32_16x16x32_bf16(a1_, bf_[j_], acc[1][j_], 0, 0, 0); \
            acc[2][j_] = __builtin_amdgcn_mfma_f32_16x16x32_bf16(a2_, bf_[j_], acc[2][j_], 0, 0, 0); \
            acc[3][j_] = __builtin_amdgcn_mfma_f32_16x16x32_bf16(a3_, bf_[j_], acc[3][j_], 0, 0, 0); \
        }                                                                      \
    } while (0)

// weight-set refill for global slice sg (this wave's K-half stream, 32 oc)
#define WLOAD(bf_, sg_) do { int sgl_ = (sg_);                                 \
        _Pragma("unroll")                                                      \
        for (int j_ = 0; j_ < 2; ++j_)                                         \
            bf_[j_] = wBv[((size_t)(kh * 36 + sgl_) * 256 + nb * 32 + j_ * 16 + ln) * 4 + lk]; \
    } while (0)

    BAR_LGKM();   // metadata ready; sOff dead -> windows writable

    STAGE(0);     // each stream stages its phase-0 window (cc = khp*4)
    BAR_LGKM();   // windows visible

    // prologue: pack pair0 (taps 0,1; one tap per ip-group) into set0
    PACK(ip, khp * 2 + ip);
    bf16x8 bfE[2], bfO[2];
    WLOAD(bfE, 0);
    WLOAD(bfO, 1);
    BAR_LGKM();   // set0 visible

    for (int p = 0; p < 4; ++p) {
        int s0 = p * 9;
#pragma unroll
        for (int k = 0; k < 4; ++k) {
            // pack the NEXT consume set (opposite parity); k=3 packs the single tap 8
            if (k < 3) {
                int dset = ((k + 1) & 1) * 4;
                PACK(2 * k + 2 + ip, dset + khp * 2 + ip);
            } else if (ip == 0) {
                PACK(8, khp * 2);               // set0 slot 0 of this stream
            }
            // consume pair k from set k&1 (taps 2k, 2k+1)
            int base = (k & 1) * 4 + kh * 2;
            CONSUME(base, bfE);
            if (k < 3) WLOAD(bfE, s0 + 2 * k + 2);
            else       WLOAD(bfE, s0 + 8);      // for the tail
            CONSUME(base + 1, bfO);
            if (k < 3) WLOAD(bfO, s0 + 2 * k + 3);
            BAR_LGKM();
        }
        // tail: consume single tap 8 from set0; stage next window under it
        if (p < 3) STAGE(p + 1);
        CONSUME(kh * 2, bfE);
        BAR_LGKM();
        if (p < 3) {   // bubble: pack pair0 of next phase; reload both weight sets
            PACK(ip, khp * 2 + ip);
            WLOAD(bfE, s0 + 9);
            WLOAD(bfO, s0 + 10);
            BAR_LGKM();
        }
    }
#undef STAGE
#undef PACK
#undef CONSUME
#undef WLOAD

    // kh-combine + BN + ReLU epilogue (sOut aliases the dead window LDS)
    if (kh == 1) {
#pragma unroll
        for (int m = 0; m < 4; ++m)
#pragma unroll
            for (int j = 0; j < 2; ++j) {
                int oc = nb * 32 + j * 16 + ln;
#pragma unroll
                for (int r = 0; r < 4; ++r)
                    sOut[m * 16 + lk * 4 + r][oc] = acc[m][j][r];
            }
    }
    __syncthreads();
    if (kh == 0) {
#pragma unroll
        for (int j = 0; j < 2; ++j) {
            int oc = nb * 32 + j * 16 + ln;
            float inv = gamma[oc] * rsqrtf(rvar[oc] + 1e-5f);
            float sh  = beta[oc] - rmean[oc] * inv + bias[oc] * inv;
#pragma unroll
            for (int m = 0; m < 4; ++m) {
                int row = m * 16 + lk * 4;
                float4 rr;
                rr.x = fmaxf((acc[m][j][0] + sOut[row + 0][oc]) * inv + sh, 0.f);
                rr.y = fmaxf((acc[m][j][1] + sOut[row + 1][oc]) * inv + sh, 0.f);
                rr.z = fmaxf((acc[m][j][2] + sOut[row + 2][oc]) * inv + sh, 0.f);
                rr.w = fmaxf((acc[m][j][3] + sOut[row + 3][oc]) * inv + sh, 0.f);
                size_t oi = (((size_t)b * 256 + oc) * 64 + h) * 64 + row;
                *(float4*)(out + oi) = rr;
            }
        }
    }
}

extern "C" void kernel_launch(void* const* d_in, const int* in_sizes, int n_in,
                              void* d_out, int out_size, void* d_ws, size_t ws_size,
                              hipStream_t stream) {
    const float* x      = (const float*)d_in[0];
    const float* w_off  = (const float*)d_in[1];
    const float* b_off  = (const float*)d_in[2];
    const float* weight = (const float*)d_in[3];
    const float* bias   = (const float*)d_in[4];
    const float* gamma  = (const float*)d_in[5];
    const float* beta   = (const float*)d_in[6];
    const float* rmean  = (const float*)d_in[7];
    const float* rvar   = (const float*)d_in[8];
    float* out = (float*)d_out;

    unsigned short* wB  = (unsigned short*)d_ws;             // 589824 bf16
    unsigned short* wOB = wB + 589824;                       // 73728 bf16
    unsigned short* xT  = wOB + 73728;                       // 4 * XT_B bf16

    hipLaunchKernelGGL(prep_all, dim3(1673), dim3(256), 0, stream,
                       weight, w_off, x, wB, wOB, xT);
    hipLaunchKernelGGL(dcn_fused, dim3(256), dim3(1024), 0, stream,
                       xT, wOB, wB, b_off, bias, gamma, beta, rmean, rvar, out);
}

// Round 17
// 126.007 us; speedup vs baseline: 1.0303x; 1.0303x over previous
//
#include <hip/hip_runtime.h>
#include <math.h>

#define NH 64
#define NW 64
#define NB 4
#define CHI 256
#define CHO 256
// xT layout is CHUNK-OUTER: [B][8 cc][66*66 pos][32 ch]  (bf16, zero halo rows/cols)
#define XT_B (8 * 4356 * 32)   // per-batch elements; 4356 = 66*66

// LDS window record stride: 40 shorts (80B), 16B-aligned for b128.
#define WREC 40
#define WINSZ (594 * WREC)     // shorts per 9-row window

typedef __attribute__((ext_vector_type(8))) short bf16x8;   // MFMA A/B frag (4 VGPR)
typedef __attribute__((ext_vector_type(4))) float f32x4;    // MFMA C/D frag

static __device__ __forceinline__ unsigned short f2bf(float f) {
    unsigned int u = __float_as_uint(f);
    u += 0x7fffu + ((u >> 16) & 1u);     // RNE
    return (unsigned short)(u >> 16);
}
static __device__ __forceinline__ float bflo(unsigned int p) { return __uint_as_float(p << 16); }
// hi bf16 WITHOUT masking (low 16 bits = other channel's bf16, <=2^-8 relative junk)
static __device__ __forceinline__ float bfhij(unsigned int p) { return __uint_as_float(p); }
static __device__ __forceinline__ unsigned int pkbf(float a, float b) {
    unsigned int r;
    asm("v_cvt_pk_bf16_f32 %0, %1, %2" : "=v"(r) : "v"(a), "v"(b));
    return r;
}

// lgkm-only barrier: ds ops drained, in-flight global loads ride across.
#define BAR_LGKM() asm volatile("s_waitcnt lgkmcnt(0)\n\ts_barrier" ::: "memory")

// ws layout:
//   wB   bf16 [72][256 o][32 kin]   ks = cc*9+kt
//   wOB  bf16 [72][32 oc][32 kin]
//   xT   bf16 [B][8][4356][32]  chunk-outer

// grid 1673: [0,576) wB pack (dense f4) | [576,640) wOB pack (dense f4) |
//            [640] wOB zero tail | [641,1153) transpose | [1153,1673) halo zero
__global__ __launch_bounds__(256) void prep_all(const float* __restrict__ weight,
                                                const float* __restrict__ w_off,
                                                const float* __restrict__ x,
                                                unsigned short* __restrict__ wB,
                                                unsigned short* __restrict__ wOB,
                                                unsigned short* __restrict__ xT) {
    __shared__ unsigned short sT[64 * 134];
    int bid = blockIdx.x, tid = threadIdx.x;
    if (bid < 576) {
        int idx4 = bid * 256 + tid;
        float4 v = ((const float4*)weight)[idx4];
        float vv[4] = {v.x, v.y, v.z, v.w};
        int i0 = idx4 * 4;
#pragma unroll
        for (int j = 0; j < 4; ++j) {
            int i = i0 + j;
            int o = i / 2304, r = i - o * 2304;
            int c = r / 9, kt = r - c * 9;
            wB[(((c >> 5) * 9 + kt) * 256 + o) * 32 + (c & 31)] = f2bf(vv[j]);
        }
    } else if (bid < 640) {
        int idx4 = (bid - 576) * 256 + tid;
        if (idx4 < 15552) {
            float4 v = ((const float4*)w_off)[idx4];
            float vv[4] = {v.x, v.y, v.z, v.w};
            int i0 = idx4 * 4;
#pragma unroll
            for (int j = 0; j < 4; ++j) {
                int i = i0 + j;
                int oc = i / 2304, r = i - oc * 2304;
                int c = r / 9, kt = r - c * 9;
                wOB[(((c >> 5) * 9 + kt) * 32 + oc) * 32 + (c & 31)] = f2bf(vv[j]);
            }
        }
    } else if (bid == 640) {
        for (int k = tid; k < 11520; k += 256) {
            int ks = k / 160, r = k - ks * 160;
            int oc = 27 + r / 32, kin = r & 31;
            wOB[(ks * 32 + oc) * 32 + kin] = 0;
        }
    } else if (bid < 1153) {
        int bid2 = bid - 641;                  // 0..511
        int b = bid2 >> 7, rem = bid2 & 127;
        int y = rem >> 1, chalf = rem & 1;
        int c0 = chalf * 128;
        for (int rep = 0; rep < 8; ++rep) {
            int idx = rep * 256 + tid;         // 0..2047
            int c = idx >> 4, p4 = (idx & 15) * 4;
            const float* src = x + (((size_t)b * CHI + c0 + c) * 64 + y) * 64 + p4;
            float4 v = *(const float4*)src;
            sT[(p4 + 0) * 134 + c] = f2bf(v.x);
            sT[(p4 + 1) * 134 + c] = f2bf(v.y);
            sT[(p4 + 2) * 134 + c] = f2bf(v.z);
            sT[(p4 + 3) * 134 + c] = f2bf(v.w);
        }
        __syncthreads();
        unsigned int* xtu = (unsigned int*)xT;
        for (int rep = 0; rep < 4; ++rep) {
            int idx = rep * 256 + tid;         // 0..1023
            int px = idx >> 4, cc_l = (idx >> 2) & 3, q4 = idx & 3;
            int cc = chalf * 4 + cc_l;
            int cb = cc_l * 32 + q4 * 8;
            const unsigned int* sp = (const unsigned int*)&sT[px * 134 + cb];
            uint4 vv;
            vv.x = sp[0]; vv.y = sp[1]; vv.z = sp[2]; vv.w = sp[3];
            *(uint4*)&xtu[((size_t)(b * 8 + cc) * 4356
                           + (size_t)(y + 1) * 66 + (px + 1)) * 16 + q4 * 4] = vv;
        }
    } else {
        int flat = (bid - 1153) * 256 + tid;   // 0..133119 uints
        int b = flat / 33280, r = flat - b * 33280;
        int chunk = r / 4160, rr = r - chunk * 4160;
        int p_ = rr >> 4, ku = rr & 15;
        int pos;
        if (p_ < 66)       pos = p_;
        else if (p_ < 132) pos = 65 * 66 + (p_ - 66);
        else { int qq = p_ - 132; int side = qq & 1; int row = 1 + (qq >> 1);
               pos = row * 66 + (side ? 65 : 0); }
        unsigned int* xtu = (unsigned int*)xT;
        xtu[((size_t)(b * 8 + chunk) * 4356 + pos) * 16 + ku] = 0;
    }
}

// ---- fused: offset GEMM prologue + deformable sampling + MFMA GEMM + BN + ReLU ----
// r17 = r15 (best verified, 45.9us) + intra-interval chain shortening:
//   (1) consume ds_reads hoisted around PACK issue; (2) s_setprio(1) around MFMA
//   clusters; (3) phase-crossing WLOADs moved from bubble into tail.
// Slot/barrier topology identical to r15. 512 thr, nb(4: 64-oc) x kh(2).
__global__ __launch_bounds__(512, 2) void dcn_fused(
        const unsigned short* __restrict__ xT,
        const unsigned short* __restrict__ wOB,
        const unsigned short* __restrict__ wB,
        const float* __restrict__ b_off,
        const float* __restrict__ bias, const float* __restrict__ gamma,
        const float* __restrict__ beta, const float* __restrict__ rmean,
        const float* __restrict__ rvar, float* __restrict__ out) {
    // LDS: s_po [0,9216) s_cw [9216,18432) fixed.
    //   sA   [18432,59392): 8 slots (2 sets x 2 slices x 2 streams) x 64px x 40B
    //   sWin [59392,154432): 2 windows x 594 rec x 80B = 47520B each
    //   sOff (33792B) and sOut (66560B) alias sWin (prologue / epilogue only)
    __shared__ __align__(16) unsigned char smem[154432];
    int4*   s_po = (int4*)smem;                                 // [576], pre-scaled x WREC
    float4* s_cw = (float4*)(smem + 9216);                      // [576]
    unsigned short* sA = (unsigned short*)(smem + 18432);
    unsigned short* sWin = (unsigned short*)(smem + 59392);
    float* sOff = (float*)(smem + 59392);
    float (*sOut)[260] = (float(*)[260])(smem + 59392);         // [64][260]

    int id = blockIdx.x;                        // 256 blocks
    int xcd = id & 7, sl = id >> 3;             // 32 blocks per XCD
    int b = xcd >> 1;                           // batch pinned to XCD pair (xT L2 reuse)
    int h = (xcd & 1) * 32 + sl;                // output row

    int tid = threadIdx.x;
    int lane = tid & 63, q = tid >> 6;
    int ln = lane & 15, lk = lane >> 4;
    int nb = q & 3, kh = q >> 2;                // consumer: 64-oc group, K-half

    const unsigned short* xTfull = xT + (size_t)b * XT_B;
    const bf16x8* wOBv = (const bf16x8*)wOB;
    const bf16x8* wBv  = (const bf16x8*)wB;

    // ---- offset-conv prologue: om = xT . wOB  (M=64 px, N=32 oc, K=2304) ----
    {
        int omt = q & 1, okq = q >> 1;
        int px0 = omt * 32 + ln;
        int posb = (h + 1) * 66 + 1 + px0;
        f32x4 oa00 = {0.f,0.f,0.f,0.f}, oa01 = {0.f,0.f,0.f,0.f};
        f32x4 oa10 = {0.f,0.f,0.f,0.f}, oa11 = {0.f,0.f,0.f,0.f};
        for (int cc = okq * 2; cc < okq * 2 + 2; ++cc) {
#pragma unroll
            for (int kt = 0; kt < 9; ++kt) {
                int pos = posb + (kt / 3 - 1) * 66 + (kt % 3 - 1);
                bf16x8 A0 = *(const bf16x8*)&xTfull[((size_t)cc * 4356 + pos) * 32 + lk * 8];
                bf16x8 A1 = *(const bf16x8*)&xTfull[((size_t)cc * 4356 + pos + 16) * 32 + lk * 8];
                bf16x8 B0 = wOBv[((size_t)(cc * 9 + kt) * 32 + ln) * 4 + lk];
                bf16x8 B1 = wOBv[((size_t)(cc * 9 + kt) * 32 + 16 + ln) * 4 + lk];
                oa00 = __builtin_amdgcn_mfma_f32_16x16x32_bf16(A0, B0, oa00, 0, 0, 0);
                oa01 = __builtin_amdgcn_mfma_f32_16x16x32_bf16(A0, B1, oa01, 0, 0, 0);
                oa10 = __builtin_amdgcn_mfma_f32_16x16x32_bf16(A1, B0, oa10, 0, 0, 0);
                oa11 = __builtin_amdgcn_mfma_f32_16x16x32_bf16(A1, B1, oa11, 0, 0, 0);
            }
        }
#pragma unroll
        for (int r = 0; r < 4; ++r) {
            int row0 = okq * 64 + omt * 32 + lk * 4 + r;
            sOff[row0 * 33 + ln]            = oa00[r];
            sOff[row0 * 33 + 16 + ln]       = oa01[r];
            sOff[(row0 + 16) * 33 + ln]     = oa10[r];
            sOff[(row0 + 16) * 33 + 16 + ln]= oa11[r];
        }
    }
    BAR_LGKM();

    // ---- bilinear metadata; corner offsets pre-scaled by WREC (shorts) ----
    for (int p = tid; p < 576; p += 512) {
        int k = p >> 6, pwl = p & 63;
        float dy = b_off[k], dx = b_off[k + 9], mp = b_off[k + 18];
#pragma unroll
        for (int jq = 0; jq < 4; ++jq) {
            dy += sOff[(jq * 64 + pwl) * 33 + k];
            dx += sOff[(jq * 64 + pwl) * 33 + k + 9];
            mp += sOff[(jq * 64 + pwl) * 33 + k + 18];
        }
        float mv = 1.f / (1.f + __expf(-mp));
        float py  = (float)h   + (float)(k / 3 - 1) + dy;
        float pxf = (float)pwl + (float)(k % 3 - 1) + dx;
        float y0f = floorf(py), x0f = floorf(pxf);
        int y0 = (int)y0f, x0 = (int)x0f;
        float ly = py - y0f, lx = pxf - x0f;
        int y0c = min(max(y0, -1), 64), y1c = min(max(y0 + 1, -1), 64);
        int x0c = min(max(x0, -1), 64), x1c = min(max(x0 + 1, -1), 64);
        int wy0 = min(max(y0c + 4 - h, 0), 8), wy1 = min(max(y1c + 4 - h, 0), 8);
        int rx0 = x0c + 1, rx1 = x1c + 1;
        s_po[p] = make_int4((wy0 * 66 + rx0) * WREC, (wy0 * 66 + rx1) * WREC,
                            (wy1 * 66 + rx0) * WREC, (wy1 * 66 + rx1) * WREC);
        s_cw[p] = make_float4((1.f - ly) * (1.f - lx) * mv, (1.f - ly) * lx * mv,
                              ly * (1.f - lx) * mv,         ly * lx * mv);
    }

    // producer role: cg8 (16B chunk of an 80B record), pxl 0..63, khp stream (== kh)
    int cg8 = tid & 3, pxl = (tid >> 2) & 63, khp = tid >> 8;

    f32x4 zf = {0.f, 0.f, 0.f, 0.f};
    f32x4 acc[4][4] = {{zf,zf,zf,zf},{zf,zf,zf,zf},{zf,zf,zf,zf},{zf,zf,zf,zf}};

// stage 9-row window (dense 16B granules); dst record stride WREC (80B)
#define STAGE(pp) do { int ccg_ = khp * 4 + (pp);                              \
        unsigned short* wd_ = sWin + khp * WINSZ;                              \
        int t_ = tid & 255;                                                    \
        for (int rr_ = 0; rr_ < 10; ++rr_) {                                   \
            int idx_ = rr_ * 256 + t_;                                         \
            if (idx_ < 2376) {                                                 \
                int wr_ = idx_ / 264, rg_ = idx_ - wr_ * 264;                  \
                int pr_ = rg_ >> 2, g_ = rg_ & 3;                              \
                int gy_ = min(max(h - 3 + wr_, 0), 65);                        \
                const unsigned short* sp_ = xTfull                             \
                    + ((size_t)(ccg_ * 4356 + gy_ * 66) << 5) + rg_ * 8;       \
                *(uint4*)(wd_ + (size_t)(wr_ * 66 + pr_) * WREC + g_ * 8)      \
                    = *(const uint4*)sp_;                                      \
            }                                                                  \
        }                                                                      \
    } while (0)

// gather 4 corners of tap kt (offsets pre-scaled), weight, pack, write sA slot
#define PACK(kt_, buf_) do {                                                   \
        int4 o4_ = s_po[(kt_) * 64 + pxl];                                     \
        const unsigned short* wb_ = sWin + khp * WINSZ + cg8 * 8;              \
        uint4 C00 = *(const uint4*)(wb_ + (size_t)o4_.x);                      \
        uint4 C01 = *(const uint4*)(wb_ + (size_t)o4_.y);                      \
        uint4 C10 = *(const uint4*)(wb_ + (size_t)o4_.z);                      \
        uint4 C11 = *(const uint4*)(wb_ + (size_t)o4_.w);                      \
        float4 w_ = s_cw[(kt_) * 64 + pxl];                                    \
        uint4 pk_;                                                             \
        pk_.x = pkbf(w_.x*bflo(C00.x)+w_.y*bflo(C01.x)+w_.z*bflo(C10.x)+w_.w*bflo(C11.x), \
                     w_.x*bfhij(C00.x)+w_.y*bfhij(C01.x)+w_.z*bfhij(C10.x)+w_.w*bfhij(C11.x)); \
        pk_.y = pkbf(w_.x*bflo(C00.y)+w_.y*bflo(C01.y)+w_.z*bflo(C10.y)+w_.w*bflo(C11.y), \
                     w_.x*bfhij(C00.y)+w_.y*bfhij(C01.y)+w_.z*bfhij(C10.y)+w_.w*bfhij(C11.y)); \
        pk_.z = pkbf(w_.x*bflo(C00.z)+w_.y*bflo(C01.z)+w_.z*bflo(C10.z)+w_.w*bflo(C11.z), \
                     w_.x*bfhij(C00.z)+w_.y*bfhij(C01.z)+w_.z*bfhij(C10.z)+w_.w*bfhij(C11.z)); \
        pk_.w = pkbf(w_.x*bflo(C00.w)+w_.y*bflo(C01.w)+w_.z*bflo(C10.w)+w_.w*bflo(C11.w), \
                     w_.x*bfhij(C00.w)+w_.y*bfhij(C01.w)+w_.z*bfhij(C10.w)+w_.w*bfhij(C11.w)); \
        *(uint4*)&sA[(buf_) * 2560 + pxl * 40 + cg8 * 8] = pk_;                \
    } while (0)

// hoisted consume-reads and setprio-wrapped MFMA cluster
#define LOADA(slot_, A_) do {                                                  \
        const unsigned short* pA_ = &sA[(slot_) * 2560];                       \
        A_[0] = *(const bf16x8*)&pA_[(0 * 16 + ln) * 40 + lk * 8];             \
        A_[1] = *(const bf16x8*)&pA_[(1 * 16 + ln) * 40 + lk * 8];             \
        A_[2] = *(const bf16x8*)&pA_[(2 * 16 + ln) * 40 + lk * 8];             \
        A_[3] = *(const bf16x8*)&pA_[(3 * 16 + ln) * 40 + lk * 8];             \
    } while (0)

#define MFMAS(A_, bf_) do {                                                    \
        __builtin_amdgcn_s_setprio(1);                                         \
        _Pragma("unroll")                                                      \
        for (int j_ = 0; j_ < 4; ++j_) {                                       \
            acc[0][j_] = __builtin_amdgcn_mfma_f32_16x16x32_bf16(A_[0], bf_[j_], acc[0][j_], 0, 0, 0); \
            acc[1][j_] = __builtin_amdgcn_mfma_f32_16x16x32_bf16(A_[1], bf_[j_], acc[1][j_], 0, 0, 0); \
            acc[2][j_] = __builtin_amdgcn_mfma_f32_16x16x32_bf16(A_[2], bf_[j_], acc[2][j_], 0, 0, 0); \
            acc[3][j_] = __builtin_amdgcn_mfma_f32_16x16x32_bf16(A_[3], bf_[j_], acc[3][j_], 0, 0, 0); \
        }                                                                      \
        __builtin_amdgcn_s_setprio(0);                                         \
    } while (0)

// weight-set refill for global slice sg (this wave's K-half stream)
#define WLOAD(bf_, sg_) do { int sgl_ = (sg_);                                 \
        _Pragma("unroll")                                                      \
        for (int j_ = 0; j_ < 4; ++j_)                                         \
            bf_[j_] = wBv[((size_t)(kh * 36 + sgl_) * 256 + nb * 64 + j_ * 16 + ln) * 4 + lk]; \
    } while (0)

    BAR_LGKM();   // metadata ready; sOff dead -> windows writable

    STAGE(0);     // each stream stages its phase-0 window (cc = khp*4)
    BAR_LGKM();   // windows visible

    // prologue: pack pair0 (taps 0,1) into set0; load weights for slices 0,1
    PACK(0, khp * 2 + 0);
    PACK(1, khp * 2 + 1);
    bf16x8 bfE[4], bfO[4];
    WLOAD(bfE, 0);
    WLOAD(bfO, 1);
    BAR_LGKM();   // set0 visible

    for (int p = 0; p < 4; ++p) {
        int s0 = p * 9;
#pragma unroll
        for (int k = 0; k < 4; ++k) {
            int base = (k & 1) * 4 + kh * 2;
            bf16x8 aA[4], aB[4];
            LOADA(base, aA);                    // sliceA reads issue first
            if (k < 3) {
                int dset = ((k + 1) & 1) * 4;
                PACK(2 * k + 2, dset + khp * 2 + 0);
                PACK(2 * k + 3, dset + khp * 2 + 1);
            } else {
                PACK(8, khp * 2 + 0);           // set0 slot 0 of this stream
            }
            LOADA(base + 1, aB);                // sliceB reads land under PACK VALU
            MFMAS(aA, bfE);
            if (k < 3) WLOAD(bfE, s0 + 2 * k + 2);
            else       WLOAD(bfE, s0 + 8);      // for the tail
            MFMAS(aB, bfO);
            if (k < 3) WLOAD(bfO, s0 + 2 * k + 3);
            BAR_LGKM();
        }
        // tail: consume single tap 8 from set0; stage next window under it;
        // next-phase weight loads issue here so latency hides under MFMAs
        if (p < 3) STAGE(p + 1);
        {
            bf16x8 aT[4];
            LOADA(kh * 2, aT);
            MFMAS(aT, bfE);
        }
        if (p < 3) { WLOAD(bfE, s0 + 9); WLOAD(bfO, s0 + 10); }
        BAR_LGKM();
        if (p < 3) {   // bubble: pack pair0 of next phase (weights already in flight)
            PACK(0, khp * 2 + 0);
            PACK(1, khp * 2 + 1);
            BAR_LGKM();
        }
    }
#undef STAGE
#undef PACK
#undef LOADA
#undef MFMAS
#undef WLOAD

    // kh-combine + BN + ReLU epilogue (sOut aliases the dead window LDS)
    if (kh == 1) {
#pragma unroll
        for (int m = 0; m < 4; ++m)
#pragma unroll
            for (int j = 0; j < 4; ++j) {
                int oc = nb * 64 + j * 16 + ln;
#pragma unroll
                for (int r = 0; r < 4; ++r)
                    sOut[m * 16 + lk * 4 + r][oc] = acc[m][j][r];
            }
    }
    __syncthreads();
    if (kh == 0) {
#pragma unroll
        for (int j = 0; j < 4; ++j) {
            int oc = nb * 64 + j * 16 + ln;
            float inv = gamma[oc] * rsqrtf(rvar[oc] + 1e-5f);
            float sh  = beta[oc] - rmean[oc] * inv + bias[oc] * inv;
#pragma unroll
            for (int m = 0; m < 4; ++m) {
                int row = m * 16 + lk * 4;
                float4 rr;
                rr.x = fmaxf((acc[m][j][0] + sOut[row + 0][oc]) * inv + sh, 0.f);
                rr.y = fmaxf((acc[m][j][1] + sOut[row + 1][oc]) * inv + sh, 0.f);
                rr.z = fmaxf((acc[m][j][2] + sOut[row + 2][oc]) * inv + sh, 0.f);
                rr.w = fmaxf((acc[m][j][3] + sOut[row + 3][oc]) * inv + sh, 0.f);
                size_t oi = (((size_t)b * 256 + oc) * 64 + h) * 64 + row;
                *(float4*)(out + oi) = rr;
            }
        }
    }
}

extern "C" void kernel_launch(void* const* d_in, const int* in_sizes, int n_in,
                              void* d_out, int out_size, void* d_ws, size_t ws_size,
                              hipStream_t stream) {
    const float* x      = (const float*)d_in[0];
    const float* w_off  = (const float*)d_in[1];
    const float* b_off  = (const float*)d_in[2];
    const float* weight = (const float*)d_in[3];
    const float* bias   = (const float*)d_in[4];
    const float* gamma  = (const float*)d_in[5];
    const float* beta   = (const float*)d_in[6];
    const float* rmean  = (const float*)d_in[7];
    const float* rvar   = (const float*)d_in[8];
    float* out = (float*)d_out;

    unsigned short* wB  = (unsigned short*)d_ws;             // 589824 bf16
    unsigned short* wOB = wB + 589824;                       // 73728 bf16
    unsigned short* xT  = wOB + 73728;                       // 4 * XT_B bf16

    hipLaunchKernelGGL(prep_all, dim3(1673), dim3(256), 0, stream,
                       weight, w_off, x, wB, wOB, xT);
    hipLaunchKernelGGL(dcn_fused, dim3(256), dim3(512), 0, stream,
                       xT, wOB, wB, b_off, bias, gamma, beta, rmean, rvar, out);
}